// Round 7
// baseline (273.757 us; speedup 1.0000x reference)
//
#include <hip/hip_runtime.h>
#include <hip/hip_bf16.h>

// ---- problem constants (fixed by setup_inputs) ----
#define NB 2
#define LQ 19947
#define LV 19947
#define DM 256
#define NH 8
#define NL 4
#define NP 4
#define MROWS (NB*LQ)      // 39894
#define MPAD  39936        // 156*256
#define QPB 2              // queries per block in msda_sample

__device__ __constant__ int c_lvlH[4] = {100, 50, 25, 13};
__device__ __constant__ int c_lvlW[4] = {150, 75, 38, 19};
__device__ __constant__ int c_lvlS[4] = {0, 15000, 18750, 19700};

typedef __attribute__((ext_vector_type(8))) short short8;   // 8 bf16 (4 VGPRs)
typedef __attribute__((ext_vector_type(4))) float f32x4;
typedef __attribute__((ext_vector_type(2))) float f32x2;

__device__ __forceinline__ unsigned short f2bf(float f) {   // RTNE fp32->bf16
  unsigned u = __float_as_uint(f);
  u += 0x7FFFu + ((u >> 16) & 1u);
  return (unsigned short)(u >> 16);
}
__device__ __forceinline__ float bfl(unsigned u) { return __uint_as_float(u << 16); }
__device__ __forceinline__ float bfh(unsigned u) { return __uint_as_float(u & 0xFFFF0000u); }
__device__ __forceinline__ f32x2 up2(unsigned u) {
  f32x2 r; r.x = __uint_as_float(u << 16); r.y = __uint_as_float(u & 0xFFFF0000u); return r;
}
// packed RTNE fp32x2 -> bf16x2 (1 inst; bit-identical to f2bf for finite inputs)
__device__ __forceinline__ unsigned cvtpk(float lo, float hi) {
  unsigned r;
  asm("v_cvt_pk_bf16_f32 %0, %1, %2" : "=v"(r) : "v"(lo), "v"(hi));
  return r;
}
// 8 fp32 -> short8 bf16 fragment
__device__ __forceinline__ short8 cvt8(const float4& x, const float4& y) {
  union { uint4 u; short8 s; } v;
  v.u.x = cvtpk(x.x, x.y); v.u.y = cvtpk(x.z, x.w);
  v.u.z = cvtpk(y.x, y.y); v.u.w = cvtpk(y.z, y.w);
  return v.s;
}

// ===========================================================================
// FRONT GEMM v5: v4's zero-barrier whole-B structure with its two measured
// defects fixed (R6 counters: 5.59M bank-conflict cycles from the (c&3)<<4
// swizzle on a 512B col stride; occupancy 18% at 4 waves/block):
//  - full-spread swizzle: byte_in_col ^= (c&7)<<4  -> uniform 8 lanes per
//    16B granule on ds_read_b128 (the conflict-free floor); XOR computed
//    per K-step since ks*64 overlaps the swizzle bits.
//  - 512-thread blocks (8 waves x 32 rows = 256 rows/block), 64KB LDS,
//    2 blocks/CU -> 16 waves/CU (2x v4).
//  blockIdx.y<2: value = x @ Wv^T + b_val  (Nn=256)
//  blockIdx.y>=2: oc   = q @ [Wsamp;Wattn]^T + [b_samp;b_attn]  (Nn=384)
// ===========================================================================
__global__ __launch_bounds__(512, 4) void gemm_front(
    const float* __restrict__ xin, const float* __restrict__ query,
    const float* __restrict__ Wv, const float* __restrict__ Wsamp,
    const float* __restrict__ Wattn,
    const float* __restrict__ b_val, const float* __restrict__ b_samp,
    const float* __restrict__ b_attn,
    unsigned short* __restrict__ value, unsigned short* __restrict__ oc)
{
  const float* Af; const float* Bf; const float* biasp;
  unsigned short* Cp; int Nn, cb, bro;
  if (blockIdx.y < 2) {
    Af = xin; Bf = Wv; cb = blockIdx.y; bro = cb * 128;
    biasp = b_val + cb * 128; Cp = value; Nn = 256;
  } else {
    Af = query; cb = blockIdx.y - 2; Cp = oc; Nn = 384;
    if (cb < 2) { Bf = Wsamp; bro = cb * 128; biasp = b_samp + cb * 128; }
    else        { Bf = Wattn; bro = 0;        biasp = b_attn; }
  }
  const int colBase = cb * 128;

  __shared__ alignas(16) short Bs[128 * 256];   // 64 KB, [col][k] swizzled

  const int t = threadIdx.x;
  const size_t rowBase = (size_t)blockIdx.x * 256;

  // ---- A prefetch geometry (issue before barrier; overlaps B staging) ----
  const int wv = t >> 6, l = t & 63;
  const int row0 = (int)rowBase + wv * 32 + (l & 15);
  const int r0c = row0 < MROWS - 1 ? row0 : MROWS - 1;          // clamp (pad rows unread)
  const int r1c = row0 + 16 < MROWS - 1 ? row0 + 16 : MROWS - 1;
  const int kq = (l >> 4) * 8;
  const float* a0p = Af + (size_t)r0c * 256 + kq;
  const float* a1p = Af + (size_t)r1c * 256 + kq;

  float4 c00, c01, c10, c11, n00, n01, n10, n11;
#define LDA(s00,s01,s10,s11,KS) do { \
    const float* p0 = a0p + (KS) * 32; const float* p1 = a1p + (KS) * 32; \
    s00 = *(const float4*)p0; s01 = *(const float4*)(p0 + 4); \
    s10 = *(const float4*)p1; s11 = *(const float4*)(p1 + 4); } while (0)
  LDA(c00, c01, c10, c11, 0);
  LDA(n00, n01, n10, n11, 1);

  // ---- stage B once: 512 threads, 4 threads/col, 64B of k each ----
  {
    const int c   = t >> 2;                 // 0..127
    const int sub = t & 3;                  // k-bytes [sub*128, sub*128+128)
    const unsigned swz = (unsigned)((c & 7) << 4);
    const float* wp = Bf + (size_t)(bro + c) * 256 + sub * 64;
    char* cbp = (char*)Bs + c * 512;
    float4 s0, s1, s2, s3, u0, u1, u2, u3;
#define LDWB(d0,d1,d2,d3,B) do { const float* p = wp + (B) * 16; \
    d0 = *(const float4*)p;       d1 = *(const float4*)(p + 4); \
    d2 = *(const float4*)(p + 8); d3 = *(const float4*)(p + 12); } while (0)
#define STWB(d0,d1,d2,d3,B) do { uint4 w0, w1; \
    w0.x = cvtpk(d0.x, d0.y); w0.y = cvtpk(d0.z, d0.w); \
    w0.z = cvtpk(d1.x, d1.y); w0.w = cvtpk(d1.z, d1.w); \
    w1.x = cvtpk(d2.x, d2.y); w1.y = cvtpk(d2.z, d2.w); \
    w1.z = cvtpk(d3.x, d3.y); w1.w = cvtpk(d3.z, d3.w); \
    *(uint4*)(cbp + (((unsigned)(sub * 128 + (B) * 32 +  0)) ^ swz)) = w0; \
    *(uint4*)(cbp + (((unsigned)(sub * 128 + (B) * 32 + 16)) ^ swz)) = w1; } while (0)
    LDWB(s0, s1, s2, s3, 0); LDWB(u0, u1, u2, u3, 1);
    STWB(s0, s1, s2, s3, 0); LDWB(s0, s1, s2, s3, 2);
    STWB(u0, u1, u2, u3, 1); LDWB(u0, u1, u2, u3, 3);
    STWB(s0, s1, s2, s3, 2);
    STWB(u0, u1, u2, u3, 3);
#undef LDWB
#undef STWB
  }
  __syncthreads();                          // the ONLY barrier

  // ---- zero-barrier K-loop ----
  const char* lbase = (const char*)Bs + (l & 15) * 512;
  const unsigned rsz = (unsigned)((l & 7) << 4);
  const unsigned k16 = (unsigned)((l >> 4) * 16);

  f32x4 acc[2][8];
  const f32x4 z = {0.f, 0.f, 0.f, 0.f};
  #pragma unroll
  for (int fi = 0; fi < 2; ++fi)
    #pragma unroll
    for (int j = 0; j < 8; ++j) acc[fi][j] = z;

  short8 bq[8], bn[8];
  {
    const unsigned koff = k16 ^ rsz;
    #pragma unroll
    for (int j = 0; j < 8; ++j) bq[j] = *(const short8*)(lbase + koff + j * 8192);
  }

  #pragma unroll
  for (int ks = 0; ks < 8; ++ks) {
    if (ks < 7) {
      const unsigned koffn = (k16 + (unsigned)((ks + 1) * 64)) ^ rsz;
      #pragma unroll
      for (int j = 0; j < 8; ++j) bn[j] = *(const short8*)(lbase + koffn + j * 8192);
    }
    const short8 af0 = cvt8(c00, c01);
    const short8 af1 = cvt8(c10, c11);
    c00 = n00; c01 = n01; c10 = n10; c11 = n11;
    if (ks < 6) LDA(n00, n01, n10, n11, ks + 2);
    #pragma unroll
    for (int j = 0; j < 8; ++j) {
      acc[0][j] = __builtin_amdgcn_mfma_f32_16x16x32_bf16(bq[j], af0, acc[0][j], 0, 0, 0);
      acc[1][j] = __builtin_amdgcn_mfma_f32_16x16x32_bf16(bq[j], af1, acc[1][j], 0, 0, 0);
    }
    #pragma unroll
    for (int j = 0; j < 8; ++j) bq[j] = bn[j];
  }
#undef LDA

  // ---- epilogue: bias + bf16 store ----
  const int lc = (l >> 4) * 4;
  #pragma unroll
  for (int j = 0; j < 8; ++j) {
    const float4 bj = *(const float4*)(biasp + j * 16 + lc);
    #pragma unroll
    for (int fi = 0; fi < 2; ++fi) {
      const int row = row0 + fi * 16;
      uint2 st;
      st.x = (unsigned)f2bf(acc[fi][j][0] + bj.x) | ((unsigned)f2bf(acc[fi][j][1] + bj.y) << 16);
      st.y = (unsigned)f2bf(acc[fi][j][2] + bj.z) | ((unsigned)f2bf(acc[fi][j][3] + bj.w) << 16);
      *(uint2*)(Cp + (size_t)row * Nn + colBase + j * 16 + lc) = st;
    }
  }
}

// ===========================================================================
// Output GEMM v5: same fixes; A (accb, bf16) loads directly to fragments,
// B = W_out staged once. fp32 stores, row guard at MROWS.
// ===========================================================================
__global__ __launch_bounds__(512, 4) void gemm_out(
    const unsigned short* __restrict__ Ab, const float* __restrict__ Wof,
    const float* __restrict__ bias, float* __restrict__ Cp)
{
  __shared__ alignas(16) short Bs[128 * 256];   // 64 KB

  const int t = threadIdx.x;
  const size_t rowBase = (size_t)blockIdx.x * 256;
  const int colBase = blockIdx.y * 128;

  const int wv = t >> 6, l = t & 63;
  const int row0 = (int)rowBase + wv * 32 + (l & 15);
  const int kq = (l >> 4) * 8;
  const unsigned short* a0p = Ab + (size_t)row0 * 256 + kq;   // MPAD rows all valid
  const unsigned short* a1p = a0p + 16 * 256;

  short8 afc0, afc1, afn0, afn1;
#define LDA2(d0,d1,KS) do { \
    d0 = *(const short8*)(a0p + (KS) * 32); \
    d1 = *(const short8*)(a1p + (KS) * 32); } while (0)
  LDA2(afc0, afc1, 0);
  LDA2(afn0, afn1, 1);

  // ---- stage B once ----
  {
    const int c   = t >> 2;
    const int sub = t & 3;
    const unsigned swz = (unsigned)((c & 7) << 4);
    const float* wp = Wof + (size_t)(colBase + c) * 256 + sub * 64;
    char* cbp = (char*)Bs + c * 512;
    float4 s0, s1, s2, s3, u0, u1, u2, u3;
#define LDWB(d0,d1,d2,d3,B) do { const float* p = wp + (B) * 16; \
    d0 = *(const float4*)p;       d1 = *(const float4*)(p + 4); \
    d2 = *(const float4*)(p + 8); d3 = *(const float4*)(p + 12); } while (0)
#define STWB(d0,d1,d2,d3,B) do { uint4 w0, w1; \
    w0.x = cvtpk(d0.x, d0.y); w0.y = cvtpk(d0.z, d0.w); \
    w0.z = cvtpk(d1.x, d1.y); w0.w = cvtpk(d1.z, d1.w); \
    w1.x = cvtpk(d2.x, d2.y); w1.y = cvtpk(d2.z, d2.w); \
    w1.z = cvtpk(d3.x, d3.y); w1.w = cvtpk(d3.z, d3.w); \
    *(uint4*)(cbp + (((unsigned)(sub * 128 + (B) * 32 +  0)) ^ swz)) = w0; \
    *(uint4*)(cbp + (((unsigned)(sub * 128 + (B) * 32 + 16)) ^ swz)) = w1; } while (0)
    LDWB(s0, s1, s2, s3, 0); LDWB(u0, u1, u2, u3, 1);
    STWB(s0, s1, s2, s3, 0); LDWB(s0, s1, s2, s3, 2);
    STWB(u0, u1, u2, u3, 1); LDWB(u0, u1, u2, u3, 3);
    STWB(s0, s1, s2, s3, 2);
    STWB(u0, u1, u2, u3, 3);
#undef LDWB
#undef STWB
  }
  __syncthreads();                          // the ONLY barrier

  const char* lbase = (const char*)Bs + (l & 15) * 512;
  const unsigned rsz = (unsigned)((l & 7) << 4);
  const unsigned k16 = (unsigned)((l >> 4) * 16);

  f32x4 acc[2][8];
  const f32x4 z = {0.f, 0.f, 0.f, 0.f};
  #pragma unroll
  for (int fi = 0; fi < 2; ++fi)
    #pragma unroll
    for (int j = 0; j < 8; ++j) acc[fi][j] = z;

  short8 bq[8], bn[8];
  {
    const unsigned koff = k16 ^ rsz;
    #pragma unroll
    for (int j = 0; j < 8; ++j) bq[j] = *(const short8*)(lbase + koff + j * 8192);
  }

  #pragma unroll
  for (int ks = 0; ks < 8; ++ks) {
    if (ks < 7) {
      const unsigned koffn = (k16 + (unsigned)((ks + 1) * 64)) ^ rsz;
      #pragma unroll
      for (int j = 0; j < 8; ++j) bn[j] = *(const short8*)(lbase + koffn + j * 8192);
    }
    const short8 af0 = afc0;
    const short8 af1 = afc1;
    afc0 = afn0; afc1 = afn1;
    if (ks < 6) LDA2(afn0, afn1, ks + 2);
    #pragma unroll
    for (int j = 0; j < 8; ++j) {
      acc[0][j] = __builtin_amdgcn_mfma_f32_16x16x32_bf16(bq[j], af0, acc[0][j], 0, 0, 0);
      acc[1][j] = __builtin_amdgcn_mfma_f32_16x16x32_bf16(bq[j], af1, acc[1][j], 0, 0, 0);
    }
    #pragma unroll
    for (int j = 0; j < 8; ++j) bq[j] = bn[j];
  }
#undef LDA2

  const int lc = (l >> 4) * 4;
  #pragma unroll
  for (int j = 0; j < 8; ++j) {
    const float4 bj = *(const float4*)(bias + colBase + j * 16 + lc);
    #pragma unroll
    for (int fi = 0; fi < 2; ++fi) {
      const int row = row0 + fi * 16;
      if (row < MROWS) {
        *(float4*)(Cp + (size_t)row * 256 + colBase + j * 16 + lc) =
            make_float4(acc[fi][j][0] + bj.x, acc[fi][j][1] + bj.y,
                        acc[fi][j][2] + bj.z, acc[fi][j][3] + bj.w);
      }
    }
  }
}

// ---------------------------------------------------------------------------
// Fused softmax + sampling (unchanged: proven 62 us).
// ---------------------------------------------------------------------------
__global__ __launch_bounds__(128) void msda_sample(
    const unsigned short* __restrict__ value,   // (NB, LV, 256) bf16
    const float* __restrict__ refp,             // (NB, LQ, 4, 2) fp32
    const unsigned short* __restrict__ oc,      // (MPAD, 384) bf16: off(256)||logits(128)
    unsigned short* __restrict__ accb)          // (MPAD, 256) bf16 out
{
  __shared__ float s_aw[QPB][128];
  __shared__ float s_ref[QPB][8];
  __shared__ alignas(16) unsigned s_pk[QPB][NH][17][8];

  const int t = threadIdx.x;
  const int bq0 = blockIdx.x * QPB;

  // Phase A: logits -> LDS (upconvert), refs
  {
    const int q = t >> 6, i = t & 63;
    const int bq = bq0 + q;
    const unsigned pw = *(const unsigned*)(oc + (size_t)bq * 384 + 256 + i * 2);
    s_aw[q][i * 2 + 0] = bfl(pw);
    s_aw[q][i * 2 + 1] = bfh(pw);
    if (t < QPB * 8) {
      const int q2 = t >> 3, j = t & 7;
      s_ref[q2][j] = refp[(size_t)(bq0 + q2) * 8 + j];
    }
  }
  __syncthreads();

  // Phase B: per-(query,head) softmax over 16 logits
  if (t < QPB * NH) {
    const int q = t >> 3, h = t & 7;
    float* aw = &s_aw[q][h * 16];
    float m = aw[0];
    #pragma unroll
    for (int i = 1; i < 16; ++i) m = fmaxf(m, aw[i]);
    float e[16]; float s = 0.f;
    #pragma unroll
    for (int i = 0; i < 16; ++i) { e[i] = __expf(aw[i] - m); s += e[i]; }
    const float inv = 1.f / s;
    #pragma unroll
    for (int i = 0; i < 16; ++i) aw[i] = e[i] * inv;
  }
  __syncthreads();

  // Phase C: byte-offsets + folded weights packed per corner-pair
  #pragma unroll
  for (int it = t; it < QPB * 128; it += 128) {
    const int q = it >> 7, rem = it & 127;     // rem = h*16 + idx
    const int h = rem >> 4, idx = rem & 15;
    const int l = idx >> 2;
    const int bq = bq0 + q;
    const unsigned po = *(const unsigned*)(oc + (size_t)bq * 384 + rem * 2);
    const int Hl = c_lvlH[l], Wl = c_lvlW[l], st = c_lvlS[l];
    const float x = s_ref[q][l * 2 + 0] * (float)Wl - 0.5f + bfl(po);
    const float y = s_ref[q][l * 2 + 1] * (float)Hl - 0.5f + bfh(po);
    const float aw = s_aw[q][rem];
    const float x0f = floorf(x), y0f = floorf(y);
    const float lx = x - x0f, ly = y - y0f;
    const int x0 = (int)x0f, y0 = (int)y0f;
    const float vx0 = (x0 >= 0 && x0 < Wl) ? 1.f : 0.f;
    const float vx1 = (x0 >= -1 && x0 < Wl - 1) ? 1.f : 0.f;
    const float vy0 = (y0 >= 0 && y0 < Hl) ? 1.f : 0.f;
    const float vy1 = (y0 >= -1 && y0 < Hl - 1) ? 1.f : 0.f;
    const int xc0 = min(max(x0, 0), Wl - 1);
    const int xc1 = min(max(x0 + 1, 0), Wl - 1);
    const int yc0 = min(max(y0, 0), Hl - 1);
    const int yc1 = min(max(y0 + 1, 0), Hl - 1);
    const int r0 = st + yc0 * Wl, r1 = st + yc1 * Wl;
    uint4 g0, g1;
    g0.x = (unsigned)(r0 + xc0) * 512u;
    g0.y = (unsigned)(r0 + xc1) * 512u;
    g0.z = __float_as_uint((1.f - lx) * (1.f - ly) * aw * (vx0 * vy0));
    g0.w = __float_as_uint(lx * (1.f - ly) * aw * (vx1 * vy0));
    g1.x = (unsigned)(r1 + xc0) * 512u;
    g1.y = (unsigned)(r1 + xc1) * 512u;
    g1.z = __float_as_uint((1.f - lx) * ly * aw * (vx0 * vy1));
    g1.w = __float_as_uint(lx * ly * aw * (vx1 * vy1));
    *(uint4*)&s_pk[q][h][idx][0] = g0;
    *(uint4*)&s_pk[q][h][idx][4] = g1;
  }
  __syncthreads();

  // Phase D: pipelined gather + packed accumulate (1 wave per query)
  const int wv = t >> 6;
  const int lane = t & 63;
  const int bq = bq0 + wv;
  const int n = bq / LQ;                       // wave-uniform
  const char* vbase = (const char*)value + (size_t)n * LV * 512;
  const int h = lane >> 3;
  const int c2 = (lane >> 2) & 1;
  const unsigned laneoff = (unsigned)(h * 64 + (lane & 3) * 16);

  f32x2 acc0 = {0.f, 0.f}, acc1 = {0.f, 0.f}, acc2 = {0.f, 0.f}, acc3 = {0.f, 0.f};

#define PKRD(i) (*(const uint4*)&s_pk[wv][h][(i)][c2 * 4])
#define GLD(o)  (*(const uint4*)(vbase + (o) + laneoff))

  uint4 pk0 = PKRD(0), pk1 = PKRD(1), pk2 = PKRD(2), pk3 = PKRD(3);
  uint4 va0 = GLD(pk0.x), vb0 = GLD(pk0.y);
  uint4 va1 = GLD(pk1.x), vb1 = GLD(pk1.y);
  uint4 va2 = GLD(pk2.x), vb2 = GLD(pk2.y);

  #pragma unroll
  for (int idx = 0; idx < 16; ++idx) {
    uint4 va3, vb3, pk4;
    if (idx < 13) { va3 = GLD(pk3.x); vb3 = GLD(pk3.y); }
    if (idx < 12) { pk4 = PKRD(idx + 4); }
    const float was = __uint_as_float(pk0.z);
    const float wbs = __uint_as_float(pk0.w);
    f32x2 wa; wa.x = was; wa.y = was;
    f32x2 wb; wb.x = wbs; wb.y = wbs;
    acc0 = acc0 + wa * up2(va0.x);
    acc1 = acc1 + wa * up2(va0.y);
    acc2 = acc2 + wa * up2(va0.z);
    acc3 = acc3 + wa * up2(va0.w);
    acc0 = acc0 + wb * up2(vb0.x);
    acc1 = acc1 + wb * up2(vb0.y);
    acc2 = acc2 + wb * up2(vb0.z);
    acc3 = acc3 + wb * up2(vb0.w);
    pk0 = pk1; pk1 = pk2; pk2 = pk3; pk3 = pk4;
    va0 = va1; va1 = va2; va2 = va3;
    vb0 = vb1; vb1 = vb2; vb2 = vb3;
  }
#undef PKRD
#undef GLD

  // combine corner pairs (lane ^ 4 flips c2)
  acc0.x += __shfl_xor(acc0.x, 4); acc0.y += __shfl_xor(acc0.y, 4);
  acc1.x += __shfl_xor(acc1.x, 4); acc1.y += __shfl_xor(acc1.y, 4);
  acc2.x += __shfl_xor(acc2.x, 4); acc2.y += __shfl_xor(acc2.y, 4);
  acc3.x += __shfl_xor(acc3.x, 4); acc3.y += __shfl_xor(acc3.y, 4);

  if (c2 == 0) {
    uint4 st;
    st.x = (unsigned)f2bf(acc0.x) | ((unsigned)f2bf(acc0.y) << 16);
    st.y = (unsigned)f2bf(acc1.x) | ((unsigned)f2bf(acc1.y) << 16);
    st.z = (unsigned)f2bf(acc2.x) | ((unsigned)f2bf(acc2.y) << 16);
    st.w = (unsigned)f2bf(acc3.x) | ((unsigned)f2bf(acc3.y) << 16);
    *(uint4*)((char*)accb + (size_t)bq * 512 + laneoff) = st;
  }
}

// ---------------------------------------------------------------------------
extern "C" void kernel_launch(void* const* d_in, const int* in_sizes, int n_in,
                              void* d_out, int out_size, void* d_ws, size_t ws_size,
                              hipStream_t stream) {
  const float* query  = (const float*)d_in[0];
  const float* refp   = (const float*)d_in[1];
  const float* xin    = (const float*)d_in[2];
  const float* W_samp = (const float*)d_in[5];
  const float* b_samp = (const float*)d_in[6];
  const float* W_attn = (const float*)d_in[7];
  const float* b_attn = (const float*)d_in[8];
  const float* W_val  = (const float*)d_in[9];
  const float* b_val  = (const float*)d_in[10];
  const float* W_out  = (const float*)d_in[11];
  const float* b_out  = (const float*)d_in[12];
  float* out = (float*)d_out;
  (void)in_sizes; (void)n_in; (void)out_size; (void)ws_size;

  char* ws = (char*)d_ws;
  unsigned short* value = (unsigned short*)(ws);                 // MPAD*256 bf16 = 20,447,232 B
  unsigned short* accb  = (unsigned short*)(ws + 20447232);      // MPAD*256 bf16
  unsigned short* oc    = (unsigned short*)(ws + 40894464);      // MPAD*384 bf16 = 30,670,848 B

  hipLaunchKernelGGL(gemm_front, dim3(156, 5), dim3(512), 0, stream,
                     xin, query, W_val, W_samp, W_attn, b_val, b_samp, b_attn,
                     value, oc);
  hipLaunchKernelGGL(msda_sample, dim3(MROWS / QPB), dim3(128), 0, stream,
                     value, refp, oc, accb);
  hipLaunchKernelGGL(gemm_out, dim3(156, 2), dim3(512), 0, stream,
                     accb, W_out, b_out, out);
}

// Round 8
// 265.557 us; speedup vs baseline: 1.0309x; 1.0309x over previous
//
#include <hip/hip_runtime.h>
#include <hip/hip_bf16.h>

// ---- problem constants (fixed by setup_inputs) ----
#define NB 2
#define LQ 19947
#define LV 19947
#define DM 256
#define NH 8
#define NL 4
#define NP 4
#define MROWS (NB*LQ)      // 39894
#define MPAD  39936        // 312*128
#define QPB 2              // queries per block in msda_sample

__device__ __constant__ int c_lvlH[4] = {100, 50, 25, 13};
__device__ __constant__ int c_lvlW[4] = {150, 75, 38, 19};
__device__ __constant__ int c_lvlS[4] = {0, 15000, 18750, 19700};

typedef __attribute__((ext_vector_type(8))) short short8;   // 8 bf16 (4 VGPRs)
typedef __attribute__((ext_vector_type(4))) float f32x4;
typedef __attribute__((ext_vector_type(2))) float f32x2;

__device__ __forceinline__ unsigned short f2bf(float f) {   // RTNE fp32->bf16
  unsigned u = __float_as_uint(f);
  u += 0x7FFFu + ((u >> 16) & 1u);
  return (unsigned short)(u >> 16);
}
__device__ __forceinline__ float bfl(unsigned u) { return __uint_as_float(u << 16); }
__device__ __forceinline__ float bfh(unsigned u) { return __uint_as_float(u & 0xFFFF0000u); }
__device__ __forceinline__ f32x2 up2(unsigned u) {
  f32x2 r; r.x = __uint_as_float(u << 16); r.y = __uint_as_float(u & 0xFFFF0000u); return r;
}
// packed RTNE fp32x2 -> bf16x2 (1 inst; bit-identical to f2bf for finite inputs)
__device__ __forceinline__ unsigned cvtpk(float lo, float hi) {
  unsigned r;
  asm("v_cvt_pk_bf16_f32 %0, %1, %2" : "=v"(r) : "v"(lo), "v"(hi));
  return r;
}

// ===========================================================================
// FRONT GEMM v6: R3-proven skeleton (dbuf LDS, 1 barrier/phase, conflict-free
// (srow&6)<<2 swizzle, 312x5 grid -> same-x blocks share an XCD) + the fix
// R3's arithmetic indicated: A prefetch depth-3 (3 reg sets, ~900cyc HBM
// cover), B depth-2 (weights L2-resident, ~200cyc). Reg-staged loads cross
// barriers without vmcnt(0) drains -> counted waits.
//  blockIdx.y<2: value = x @ Wv^T + b_val  (Nn=256)
//  blockIdx.y>=2: oc   = q @ [Wsamp;Wattn]^T + [b_samp;b_attn]  (Nn=384)
// ===========================================================================
__global__ __launch_bounds__(256, 2) void gemm_front(
    const float* __restrict__ xin, const float* __restrict__ query,
    const float* __restrict__ Wv, const float* __restrict__ Wsamp,
    const float* __restrict__ Wattn,
    const float* __restrict__ b_val, const float* __restrict__ b_samp,
    const float* __restrict__ b_attn,
    unsigned short* __restrict__ value, unsigned short* __restrict__ oc)
{
  const float* Af; const float* Bf; const float* biasp;
  unsigned short* Cp; int Nn, cb, bro;
  if (blockIdx.y < 2) {
    Af = xin; Bf = Wv; cb = blockIdx.y; bro = cb * 128;
    biasp = b_val + cb * 128; Cp = value; Nn = 256;
  } else {
    Af = query; cb = blockIdx.y - 2; Cp = oc; Nn = 384;
    if (cb < 2) { Bf = Wsamp; bro = cb * 128; biasp = b_samp + cb * 128; }
    else        { Bf = Wattn; bro = 0;        biasp = b_attn; }
  }

  __shared__ alignas(16) short As[2][128 * 32];
  __shared__ alignas(16) short Bs[2][128 * 32];

  const int t = threadIdx.x;
  const int w = t >> 6, l = t & 63;
  const int wr = w >> 1, wc = w & 1;
  const size_t rowBase = (size_t)blockIdx.x * 128;
  const int colBase = cb * 128;

  const f32x4 z = {0.f, 0.f, 0.f, 0.f};
  f32x4 acc[4][4];
  #pragma unroll
  for (int i = 0; i < 4; ++i)
    #pragma unroll
    for (int j = 0; j < 4; ++j) acc[i][j] = z;

  // staging geometry (R3-proven): thread t handles row srow, k-halves
  const int srow = t >> 1;
  const int skh  = (t & 1) * 16;
  const int swz  = (srow & 6) << 2;            // XOR short-idx bits 3-4 w/ row bits 1-2
  const int sc0  = skh ^ swz;
  const int sc1  = (skh + 8) ^ swz;
  const int arow_ok = ((int)rowBase + srow) < MROWS;
  const float* apBase = Af + ((size_t)rowBase + srow) * 256 + skh;
  const float* bpBase = Bf + (size_t)(bro + srow) * 256 + skh;
  const float4 fz4 = make_float4(0.f, 0.f, 0.f, 0.f);

  float4 a[3][4];            // A depth-3 sets (const-indexed under unroll)
  float4 b[2][4];            // B depth-2 sets

#define LD16(dst, base, K) do { const float* p_ = (base) + (K) * 32; \
    dst[0] = *(const float4*)p_;       dst[1] = *(const float4*)(p_ + 4); \
    dst[2] = *(const float4*)(p_ + 8); dst[3] = *(const float4*)(p_ + 12); } while (0)
#define LDAZ(dst, K) do { if (arow_ok) { LD16(dst, apBase, K); } \
    else { dst[0] = fz4; dst[1] = fz4; dst[2] = fz4; dst[3] = fz4; } } while (0)
#define ST16(ARR, BUF, src) do { uint4 w0_, w1_; \
    w0_.x = cvtpk(src[0].x, src[0].y); w0_.y = cvtpk(src[0].z, src[0].w); \
    w0_.z = cvtpk(src[1].x, src[1].y); w0_.w = cvtpk(src[1].z, src[1].w); \
    w1_.x = cvtpk(src[2].x, src[2].y); w1_.y = cvtpk(src[2].z, src[2].w); \
    w1_.z = cvtpk(src[3].x, src[3].y); w1_.w = cvtpk(src[3].z, src[3].w); \
    *(uint4*)&ARR[BUF][srow * 32 + sc0] = w0_; \
    *(uint4*)&ARR[BUF][srow * 32 + sc1] = w1_; } while (0)

  // prologue: tiles 0..3 (A) / 0..2 (B) in flight; tile0 staged to buf0
  LDAZ(a[0], 0); LD16(b[0], bpBase, 0);
  LDAZ(a[1], 1); LD16(b[1], bpBase, 1);
  LDAZ(a[2], 2);
  ST16(As, 0, a[0]); ST16(Bs, 0, b[0]);
  LDAZ(a[0], 3); LD16(b[0], bpBase, 2);
  __syncthreads();

  #pragma unroll
  for (int ks = 0; ks < 8; ++ks) {
    const int cur = ks & 1;
    // stage tile ks+1 into the other buffer (A from set loaded 3 phases ago)
    if (ks < 7) { ST16(As, cur ^ 1, a[(ks + 1) % 3]); ST16(Bs, cur ^ 1, b[(ks + 1) & 1]); }
    // refill freed sets: A tile ks+4 (3-phase cover), B tile ks+3 (2-phase)
    if (ks + 4 < 8) LDAZ(a[(ks + 1) % 3], ks + 4);
    if (ks + 3 < 8) LD16(b[(ks + 1) & 1], bpBase, ks + 3);
    short8 af[4], bf[4];
    #pragma unroll
    for (int i = 0; i < 4; ++i) {
      const int ar = wr * 64 + i * 16 + (l & 15);
      const int br = wc * 64 + i * 16 + (l & 15);
      const int cs = (l >> 4) * 8;
      af[i] = *(const short8*)&As[cur][ar * 32 + (cs ^ ((ar & 6) << 2))];
      bf[i] = *(const short8*)&Bs[cur][br * 32 + (cs ^ ((br & 6) << 2))];
    }
    #pragma unroll
    for (int i = 0; i < 4; ++i)
      #pragma unroll
      for (int j = 0; j < 4; ++j)
        acc[i][j] = __builtin_amdgcn_mfma_f32_16x16x32_bf16(bf[j], af[i], acc[i][j], 0, 0, 0);
    __syncthreads();
  }
#undef LD16
#undef LDAZ
#undef ST16

  const int row0 = (int)rowBase + wr * 64 + (l & 15);
  const int lc0 = wc * 64 + (l >> 4) * 4;       // local col within 128-col slice
  const int col0 = colBase + lc0;
  #pragma unroll
  for (int j = 0; j < 4; ++j) {
    const float4 bj = *(const float4*)(biasp + lc0 + j * 16);
    #pragma unroll
    for (int i = 0; i < 4; ++i) {
      const int row = row0 + i * 16;
      uint2 st;
      st.x = (unsigned)f2bf(acc[i][j][0] + bj.x) | ((unsigned)f2bf(acc[i][j][1] + bj.y) << 16);
      st.y = (unsigned)f2bf(acc[i][j][2] + bj.z) | ((unsigned)f2bf(acc[i][j][3] + bj.w) << 16);
      *(uint2*)(Cp + (size_t)row * Nn + col0 + j * 16) = st;
    }
  }
}

// ===========================================================================
// Output GEMM v6: same skeleton; A (bf16 accb) reg-staged depth-3 (uint4
// pairs, no cvt); B (fp32 W_out) depth-2 with cvt. Row guard at MROWS.
// ===========================================================================
__global__ __launch_bounds__(256, 2) void gemm_out(
    const unsigned short* __restrict__ Ab, const float* __restrict__ Wof,
    const float* __restrict__ bias, float* __restrict__ Cp)
{
  __shared__ alignas(16) short As[2][128 * 32];
  __shared__ alignas(16) short Bs[2][128 * 32];

  const int t = threadIdx.x;
  const int w = t >> 6, l = t & 63;
  const int wr = w >> 1, wc = w & 1;
  const size_t rowBase = (size_t)blockIdx.x * 128;
  const int colBase = blockIdx.y * 128;

  const f32x4 z = {0.f, 0.f, 0.f, 0.f};
  f32x4 acc[4][4];
  #pragma unroll
  for (int i = 0; i < 4; ++i)
    #pragma unroll
    for (int j = 0; j < 4; ++j) acc[i][j] = z;

  const int srow = t >> 1;
  const int skh  = (t & 1) * 16;
  const int swz  = (srow & 6) << 2;
  const int sc0  = skh ^ swz;
  const int sc1  = (skh + 8) ^ swz;
  const unsigned short* apBase = Ab + ((size_t)rowBase + srow) * 256 + skh;
  const float* bpBase = Wof + (size_t)(colBase + srow) * 256 + skh;

  uint4 av[3][2];            // A depth-3 sets (bf16, raw copy)
  float4 b[2][4];            // B depth-2 sets

#define LDA2(dst, K) do { const unsigned short* p_ = apBase + (K) * 32; \
    dst[0] = *(const uint4*)p_; dst[1] = *(const uint4*)(p_ + 8); } while (0)
#define LD16(dst, K) do { const float* p_ = bpBase + (K) * 32; \
    dst[0] = *(const float4*)p_;       dst[1] = *(const float4*)(p_ + 4); \
    dst[2] = *(const float4*)(p_ + 8); dst[3] = *(const float4*)(p_ + 12); } while (0)
#define STA(BUF, src) do { \
    *(uint4*)&As[BUF][srow * 32 + sc0] = src[0]; \
    *(uint4*)&As[BUF][srow * 32 + sc1] = src[1]; } while (0)
#define STB(BUF, src) do { uint4 w0_, w1_; \
    w0_.x = cvtpk(src[0].x, src[0].y); w0_.y = cvtpk(src[0].z, src[0].w); \
    w0_.z = cvtpk(src[1].x, src[1].y); w0_.w = cvtpk(src[1].z, src[1].w); \
    w1_.x = cvtpk(src[2].x, src[2].y); w1_.y = cvtpk(src[2].z, src[2].w); \
    w1_.z = cvtpk(src[3].x, src[3].y); w1_.w = cvtpk(src[3].z, src[3].w); \
    *(uint4*)&Bs[BUF][srow * 32 + sc0] = w0_; \
    *(uint4*)&Bs[BUF][srow * 32 + sc1] = w1_; } while (0)

  LDA2(av[0], 0); LD16(b[0], 0);
  LDA2(av[1], 1); LD16(b[1], 1);
  LDA2(av[2], 2);
  STA(0, av[0]); STB(0, b[0]);
  LDA2(av[0], 3); LD16(b[0], 2);
  __syncthreads();

  #pragma unroll
  for (int ks = 0; ks < 8; ++ks) {
    const int cur = ks & 1;
    if (ks < 7) { STA(cur ^ 1, av[(ks + 1) % 3]); STB(cur ^ 1, b[(ks + 1) & 1]); }
    if (ks + 4 < 8) LDA2(av[(ks + 1) % 3], ks + 4);
    if (ks + 3 < 8) LD16(b[(ks + 1) & 1], ks + 3);
    short8 af[4], bf[4];
    #pragma unroll
    for (int i = 0; i < 4; ++i) {
      const int ar = wr * 64 + i * 16 + (l & 15);
      const int br = wc * 64 + i * 16 + (l & 15);
      const int cs = (l >> 4) * 8;
      af[i] = *(const short8*)&As[cur][ar * 32 + (cs ^ ((ar & 6) << 2))];
      bf[i] = *(const short8*)&Bs[cur][br * 32 + (cs ^ ((br & 6) << 2))];
    }
    #pragma unroll
    for (int i = 0; i < 4; ++i)
      #pragma unroll
      for (int j = 0; j < 4; ++j)
        acc[i][j] = __builtin_amdgcn_mfma_f32_16x16x32_bf16(bf[j], af[i], acc[i][j], 0, 0, 0);
    __syncthreads();
  }
#undef LDA2
#undef LD16
#undef STA
#undef STB

  const int row0 = (int)rowBase + wr * 64 + (l & 15);
  const int col0 = colBase + wc * 64 + (l >> 4) * 4;
  #pragma unroll
  for (int j = 0; j < 4; ++j) {
    const float4 bj = *(const float4*)(bias + col0 + j * 16);
    #pragma unroll
    for (int i = 0; i < 4; ++i) {
      const int row = row0 + i * 16;
      if (row < MROWS) {
        *(float4*)(Cp + (size_t)row * 256 + col0 + j * 16) =
            make_float4(acc[i][j][0] + bj.x, acc[i][j][1] + bj.y,
                        acc[i][j][2] + bj.z, acc[i][j][3] + bj.w);
      }
    }
  }
}

// ---------------------------------------------------------------------------
// Fused softmax + sampling. One change vs the proven 62us version: s_pk head
// stride 544B -> 560B (flat s_pku) so phase-C writes spread over all 8 LDS
// 16B-granule positions (was 4 -> 4-way conflict, 1.91M cyc). Reads stay
// 2-way/broadcast (free).
// ---------------------------------------------------------------------------
__global__ __launch_bounds__(128) void msda_sample(
    const unsigned short* __restrict__ value,   // (NB, LV, 256) bf16
    const float* __restrict__ refp,             // (NB, LQ, 4, 2) fp32
    const unsigned short* __restrict__ oc,      // (MPAD, 384) bf16: off(256)||logits(128)
    unsigned short* __restrict__ accb)          // (MPAD, 256) bf16 out
{
  __shared__ float s_aw[QPB][128];
  __shared__ float s_ref[QPB][8];
  __shared__ alignas(16) unsigned s_pku[2240];  // [q]:1120w, [h]:140w(560B), [idx]:8w

  const int t = threadIdx.x;
  const int bq0 = blockIdx.x * QPB;

  // Phase A: logits -> LDS (upconvert), refs
  {
    const int q = t >> 6, i = t & 63;
    const int bq = bq0 + q;
    const unsigned pw = *(const unsigned*)(oc + (size_t)bq * 384 + 256 + i * 2);
    s_aw[q][i * 2 + 0] = bfl(pw);
    s_aw[q][i * 2 + 1] = bfh(pw);
    if (t < QPB * 8) {
      const int q2 = t >> 3, j = t & 7;
      s_ref[q2][j] = refp[(size_t)(bq0 + q2) * 8 + j];
    }
  }
  __syncthreads();

  // Phase B: per-(query,head) softmax over 16 logits
  if (t < QPB * NH) {
    const int q = t >> 3, h = t & 7;
    float* aw = &s_aw[q][h * 16];
    float m = aw[0];
    #pragma unroll
    for (int i = 1; i < 16; ++i) m = fmaxf(m, aw[i]);
    float e[16]; float s = 0.f;
    #pragma unroll
    for (int i = 0; i < 16; ++i) { e[i] = __expf(aw[i] - m); s += e[i]; }
    const float inv = 1.f / s;
    #pragma unroll
    for (int i = 0; i < 16; ++i) aw[i] = e[i] * inv;
  }
  __syncthreads();

  // Phase C: byte-offsets + folded weights packed per corner-pair
  #pragma unroll
  for (int it = t; it < QPB * 128; it += 128) {
    const int q = it >> 7, rem = it & 127;     // rem = h*16 + idx
    const int h = rem >> 4, idx = rem & 15;
    const int l = idx >> 2;
    const int bq = bq0 + q;
    const unsigned po = *(const unsigned*)(oc + (size_t)bq * 384 + rem * 2);
    const int Hl = c_lvlH[l], Wl = c_lvlW[l], st = c_lvlS[l];
    const float x = s_ref[q][l * 2 + 0] * (float)Wl - 0.5f + bfl(po);
    const float y = s_ref[q][l * 2 + 1] * (float)Hl - 0.5f + bfh(po);
    const float aw = s_aw[q][rem];
    const float x0f = floorf(x), y0f = floorf(y);
    const float lx = x - x0f, ly = y - y0f;
    const int x0 = (int)x0f, y0 = (int)y0f;
    const float vx0 = (x0 >= 0 && x0 < Wl) ? 1.f : 0.f;
    const float vx1 = (x0 >= -1 && x0 < Wl - 1) ? 1.f : 0.f;
    const float vy0 = (y0 >= 0 && y0 < Hl) ? 1.f : 0.f;
    const float vy1 = (y0 >= -1 && y0 < Hl - 1) ? 1.f : 0.f;
    const int xc0 = min(max(x0, 0), Wl - 1);
    const int xc1 = min(max(x0 + 1, 0), Wl - 1);
    const int yc0 = min(max(y0, 0), Hl - 1);
    const int yc1 = min(max(y0 + 1, 0), Hl - 1);
    const int r0 = st + yc0 * Wl, r1 = st + yc1 * Wl;
    uint4 g0, g1;
    g0.x = (unsigned)(r0 + xc0) * 512u;
    g0.y = (unsigned)(r0 + xc1) * 512u;
    g0.z = __float_as_uint((1.f - lx) * (1.f - ly) * aw * (vx0 * vy0));
    g0.w = __float_as_uint(lx * (1.f - ly) * aw * (vx1 * vy0));
    g1.x = (unsigned)(r1 + xc0) * 512u;
    g1.y = (unsigned)(r1 + xc1) * 512u;
    g1.z = __float_as_uint((1.f - lx) * ly * aw * (vx0 * vy1));
    g1.w = __float_as_uint(lx * ly * aw * (vx1 * vy1));
    unsigned* wp_ = &s_pku[q * 1120 + h * 140 + idx * 8];
    *(uint4*)wp_ = g0;
    *(uint4*)(wp_ + 4) = g1;
  }
  __syncthreads();

  // Phase D: pipelined gather + packed accumulate (1 wave per query)
  const int wv = t >> 6;
  const int lane = t & 63;
  const int bq = bq0 + wv;
  const int n = bq / LQ;                       // wave-uniform
  const char* vbase = (const char*)value + (size_t)n * LV * 512;
  const int h = lane >> 3;
  const int c2 = (lane >> 2) & 1;
  const unsigned laneoff = (unsigned)(h * 64 + (lane & 3) * 16);

  f32x2 acc0 = {0.f, 0.f}, acc1 = {0.f, 0.f}, acc2 = {0.f, 0.f}, acc3 = {0.f, 0.f};

#define PKRD(i) (*(const uint4*)&s_pku[wv * 1120 + h * 140 + (i) * 8 + c2 * 4])
#define GLD(o)  (*(const uint4*)(vbase + (o) + laneoff))

  uint4 pk0 = PKRD(0), pk1 = PKRD(1), pk2 = PKRD(2), pk3 = PKRD(3);
  uint4 va0 = GLD(pk0.x), vb0 = GLD(pk0.y);
  uint4 va1 = GLD(pk1.x), vb1 = GLD(pk1.y);
  uint4 va2 = GLD(pk2.x), vb2 = GLD(pk2.y);

  #pragma unroll
  for (int idx = 0; idx < 16; ++idx) {
    uint4 va3, vb3, pk4;
    if (idx < 13) { va3 = GLD(pk3.x); vb3 = GLD(pk3.y); }
    if (idx < 12) { pk4 = PKRD(idx + 4); }
    const float was = __uint_as_float(pk0.z);
    const float wbs = __uint_as_float(pk0.w);
    f32x2 wa; wa.x = was; wa.y = was;
    f32x2 wb; wb.x = wbs; wb.y = wbs;
    acc0 = acc0 + wa * up2(va0.x);
    acc1 = acc1 + wa * up2(va0.y);
    acc2 = acc2 + wa * up2(va0.z);
    acc3 = acc3 + wa * up2(va0.w);
    acc0 = acc0 + wb * up2(vb0.x);
    acc1 = acc1 + wb * up2(vb0.y);
    acc2 = acc2 + wb * up2(vb0.z);
    acc3 = acc3 + wb * up2(vb0.w);
    pk0 = pk1; pk1 = pk2; pk2 = pk3; pk3 = pk4;
    va0 = va1; va1 = va2; va2 = va3;
    vb0 = vb1; vb1 = vb2; vb2 = vb3;
  }
#undef PKRD
#undef GLD

  // combine corner pairs (lane ^ 4 flips c2)
  acc0.x += __shfl_xor(acc0.x, 4); acc0.y += __shfl_xor(acc0.y, 4);
  acc1.x += __shfl_xor(acc1.x, 4); acc1.y += __shfl_xor(acc1.y, 4);
  acc2.x += __shfl_xor(acc2.x, 4); acc2.y += __shfl_xor(acc2.y, 4);
  acc3.x += __shfl_xor(acc3.x, 4); acc3.y += __shfl_xor(acc3.y, 4);

  if (c2 == 0) {
    uint4 st;
    st.x = (unsigned)f2bf(acc0.x) | ((unsigned)f2bf(acc0.y) << 16);
    st.y = (unsigned)f2bf(acc1.x) | ((unsigned)f2bf(acc1.y) << 16);
    st.z = (unsigned)f2bf(acc2.x) | ((unsigned)f2bf(acc2.y) << 16);
    st.w = (unsigned)f2bf(acc3.x) | ((unsigned)f2bf(acc3.y) << 16);
    *(uint4*)((char*)accb + (size_t)bq * 512 + laneoff) = st;
  }
}

// ---------------------------------------------------------------------------
extern "C" void kernel_launch(void* const* d_in, const int* in_sizes, int n_in,
                              void* d_out, int out_size, void* d_ws, size_t ws_size,
                              hipStream_t stream) {
  const float* query  = (const float*)d_in[0];
  const float* refp   = (const float*)d_in[1];
  const float* xin    = (const float*)d_in[2];
  const float* W_samp = (const float*)d_in[5];
  const float* b_samp = (const float*)d_in[6];
  const float* W_attn = (const float*)d_in[7];
  const float* b_attn = (const float*)d_in[8];
  const float* W_val  = (const float*)d_in[9];
  const float* b_val  = (const float*)d_in[10];
  const float* W_out  = (const float*)d_in[11];
  const float* b_out  = (const float*)d_in[12];
  float* out = (float*)d_out;
  (void)in_sizes; (void)n_in; (void)out_size; (void)ws_size;

  char* ws = (char*)d_ws;
  unsigned short* value = (unsigned short*)(ws);                 // MPAD*256 bf16 = 20,447,232 B
  unsigned short* accb  = (unsigned short*)(ws + 20447232);      // MPAD*256 bf16
  unsigned short* oc    = (unsigned short*)(ws + 40894464);      // MPAD*384 bf16 = 30,670,848 B

  hipLaunchKernelGGL(gemm_front, dim3(312, 5), dim3(256), 0, stream,
                     xin, query, W_val, W_samp, W_attn, b_val, b_samp, b_attn,
                     value, oc);
  hipLaunchKernelGGL(msda_sample, dim3(MROWS / QPB), dim3(128), 0, stream,
                     value, refp, oc, accb);
  hipLaunchKernelGGL(gemm_out, dim3(312, 2), dim3(256), 0, stream,
                     accb, W_out, b_out, out);
}